// Round 14
// baseline (431.368 us; speedup 1.0000x reference)
//
#include <hip/hip_runtime.h>
#include <hip/hip_bf16.h>
#include <cstdint>

#define TOKENS 8192
#define IN_F   4096
#define OUT_F  4096

#define BM 256
#define BN 256
#define BK 64
#define NT (IN_F / BK)   // 64 K-tiles
#define THREADS 512

typedef __attribute__((ext_vector_type(8))) short bf16x8;
typedef __attribute__((ext_vector_type(4))) float f32x4;

#define GLOBAL_AS __attribute__((address_space(1)))
#define LDS_AS    __attribute__((address_space(3)))

#define BARRIER() __builtin_amdgcn_s_barrier()
#define LGKM(n)   do { asm volatile("s_waitcnt lgkmcnt(" #n ")"); \
                       __builtin_amdgcn_sched_barrier(0); } while (0)
#define VMCNT(n)  do { asm volatile("s_waitcnt vmcnt(" #n ")"); \
                       __builtin_amdgcn_sched_barrier(0); } while (0)

__device__ __forceinline__ unsigned short f2bf(float f) {
  union { float f; unsigned int u; } v;
  v.f = f;
  unsigned int r = 0x7FFFu + ((v.u >> 16) & 1u);
  return (unsigned short)((v.u + r) >> 16);
}

__device__ __forceinline__ float softplus_f(float x) {
  return log1pf(expf(x));
}

// ---------------- fused prep kernel ----------------

#define NW4 ((long long)OUT_F * IN_F / 4)
#define NX4 ((long long)TOKENS * IN_F / 4)
#define NB4 (OUT_F / 4)

__global__ void prep_kernel(const float* __restrict__ x,
                            const float* __restrict__ wmu,
                            const float* __restrict__ wrho,
                            const float* __restrict__ weps,
                            const float* __restrict__ bmu,
                            const float* __restrict__ brho,
                            const float* __restrict__ beps,
                            unsigned short* __restrict__ xb,
                            unsigned short* __restrict__ wb,
                            float* __restrict__ bias) {
  long long i = (long long)blockIdx.x * blockDim.x + threadIdx.x;
  long long stride = (long long)gridDim.x * blockDim.x;
  const long long total = NW4 + NX4 + NB4;
  for (; i < total; i += stride) {
    if (i < NW4) {
      float4 m = reinterpret_cast<const float4*>(wmu)[i];
      float4 r = reinterpret_cast<const float4*>(wrho)[i];
      float4 e = reinterpret_cast<const float4*>(weps)[i];
      ushort4 o;
      o.x = f2bf(fmaf(softplus_f(r.x), e.x, m.x));
      o.y = f2bf(fmaf(softplus_f(r.y), e.y, m.y));
      o.z = f2bf(fmaf(softplus_f(r.z), e.z, m.z));
      o.w = f2bf(fmaf(softplus_f(r.w), e.w, m.w));
      reinterpret_cast<ushort4*>(wb)[i] = o;
    } else if (i < NW4 + NX4) {
      long long j = i - NW4;
      float4 m = reinterpret_cast<const float4*>(x)[j];
      ushort4 o;
      o.x = f2bf(m.x); o.y = f2bf(m.y); o.z = f2bf(m.z); o.w = f2bf(m.w);
      reinterpret_cast<ushort4*>(xb)[j] = o;
    } else {
      long long j = i - NW4 - NX4;
      float4 m = reinterpret_cast<const float4*>(bmu)[j];
      float4 r = reinterpret_cast<const float4*>(brho)[j];
      float4 e = reinterpret_cast<const float4*>(beps)[j];
      float4 o;
      o.x = fmaf(softplus_f(r.x), e.x, m.x);
      o.y = fmaf(softplus_f(r.y), e.y, m.y);
      o.z = fmaf(softplus_f(r.z), e.z, m.z);
      o.w = fmaf(softplus_f(r.w), e.w, m.w);
      reinterpret_cast<float4*>(bias)[j] = o;
    }
  }
}

// ---------------- GEMM: 256x256, A via LDS, B DIRECT global->VGPR ----------------
// r14: B-frags bypass LDS entirely. They were read once/tile into regs anyway;
// loading straight from L2/L3 (B = 32MB, L3-resident; per 128B line = exactly
// one row's 64-col K-slice -> zero over-fetch) removes B's 64KB reads + 32KB
// stage-writes from the per-CU LDS pipe. LDS load/tile drops 256KB -> 160KB
// equiv (~1300 cyc) << MFMA 2483 cyc/SIMD: the contended pipe is now strictly
// subordinate for the first time (10 prior variants all additive at ~4400).
// B loads are wave-private VGPR loads: no cross-wave hazard, no barrier;
// double-buffered one full tile ahead (ping-pong via 2-tile unrolled bodies).
// Per-wave ledger (B issued before stage): enter t with stA(t+1)=4
// outstanding; +8 B(t+1); +4 stA(t+2); VMCNT(4) drains stA(t+1)+B(t+1),
// leaves stA(t+2). One vmcnt + one barrier per tile. A-slot liveness: slot
// (t+2)%3 last read at t-1, drained by LGKM(0) before q3 MFMA < barrier(t-1)
// < stage issue at t (r9 proof unchanged).
// A LDS swizzle: chunk ^= (row & 7) via pre-swizzled global source (linear
// global_load_lds dest) + matching XOR on ds_read (rule 21 involution).

__global__ __launch_bounds__(THREADS, 2) void gemm_bt_kernel(
    const unsigned short* __restrict__ A,   // [TOKENS][IN_F] bf16
    const unsigned short* __restrict__ B,   // [OUT_F][IN_F] bf16
    const float* __restrict__ bias,         // [OUT_F]
    float* __restrict__ C)                  // [TOKENS][OUT_F]
{
  __shared__ unsigned short lds[3 * 16384]; // A ring, 96 KiB

  const int tid  = threadIdx.x;
  const int lane = tid & 63;
  const int wave = tid >> 6;   // 0..7
  const int wm   = wave >> 2;  // 0..1
  const int wn   = wave & 3;   // 0..3

  // XCD-aware bijective block swizzle (512 = 8 XCD chunks x 64)
  const int bid = blockIdx.x;
  const int wg  = (bid & 7) * 64 + (bid >> 3);
  const int ch  = wg >> 6;
  const int idx = wg & 63;
  const int bm  = (ch >> 1) * 8 + (idx >> 3);  // 0..31
  const int bn  = (ch & 1) * 8 + (idx & 7);    // 0..15

  const int lane15 = lane & 15;
  const int cgrp   = lane >> 4;                // 0..3
  const int rdoff0 = lane15 * 64 + ((cgrp ^ (lane & 7)) * 8);
  const int rdoff1 = lane15 * 64 + (((4 + cgrp) ^ (lane & 7)) * 8);

  // A staging: per-lane pre-swizzled global source; each wave stages 32 rows
  const int srow = lane >> 3;                  // 0..7
  const int scol = ((lane & 7) ^ srow) * 8;    // swizzled 16B chunk -> elems
  const unsigned short* Asrc = A + (size_t)(bm * BM + wave * 32 + srow) * IN_F + scol;

  // B direct: per-lane base; frag (n,h) at n*16 rows, h*32 + cgrp*8 cols
  const unsigned short* Bf = B + (size_t)(bn * BN + wn * 64 + lane15) * IN_F + cgrp * 8;

  f32x4 acc[8][4] = {};

  auto stA4 = [&](int slot, int t) {
    unsigned short* dst = &lds[slot * 16384 + wave * 2048];
    const unsigned short* g = Asrc + t * BK;
#pragma unroll
    for (int i = 0; i < 4; ++i)
      __builtin_amdgcn_global_load_lds((const GLOBAL_AS void*)(g + (size_t)(i * 8) * IN_F),
                                       (LDS_AS void*)(dst + i * 512), 16, 0, 0);
  };

  auto rdA = [&](const unsigned short* Ar, int q, bf16x8 (&av)[2][2]) {
#pragma unroll
    for (int f = 0; f < 2; ++f) {
      const unsigned short* p = Ar + (wm * 128 + q * 32 + f * 16) * 64;
      av[f][0] = *reinterpret_cast<const bf16x8*>(p + rdoff0);
      av[f][1] = *reinterpret_cast<const bf16x8*>(p + rdoff1);
    }
  };
  auto rdBg = [&](int t, bf16x8 (&bv)[4][2]) {
#pragma unroll
    for (int n = 0; n < 4; ++n) {
      const unsigned short* p = Bf + (size_t)(n * 16) * IN_F + t * BK;
      bv[n][0] = *reinterpret_cast<const bf16x8*>(p);
      bv[n][1] = *reinterpret_cast<const bf16x8*>(p + 32);
    }
  };
  auto mfma16 = [&](bf16x8 (&av)[2][2], bf16x8 (&bv)[4][2], f32x4* r0, f32x4* r1) {
    __builtin_amdgcn_s_setprio(1);
#pragma unroll
    for (int kk = 0; kk < 2; ++kk) {
#pragma unroll
      for (int n = 0; n < 4; ++n) {
        r0[n] = __builtin_amdgcn_mfma_f32_16x16x32_bf16(av[0][kk], bv[n][kk], r0[n], 0, 0, 0);
        r1[n] = __builtin_amdgcn_mfma_f32_16x16x32_bf16(av[1][kk], bv[n][kk], r1[n], 0, 0, 0);
      }
    }
    __builtin_amdgcn_s_setprio(0);
  };

  bf16x8 bvA[4][2], bvB[4][2];

  // prologue: stage A(t0->slot0, t1->slot1), load B(t0) direct; drain all once
  stA4(0, 0); stA4(1, 1);
  rdBg(0, bvA);
  VMCNT(0);
  BARRIER();

  // one tile; As = slot t%3; slotStage = (t+2)%3; bvc = B(t), bvn <- B(t+1)
  auto body = [&](int t, const unsigned short* As, int slotStage,
                  bf16x8 (&bvc)[4][2], bf16x8 (&bvn)[4][2]) {
    const bool nx  = (t + 1 < NT);
    const bool pf2 = (t + 2 < NT);
    bf16x8 av0[2][2], av1[2][2];

    if (nx) rdBg(t + 1, bvn);                  // 8 vmem (B first: ledger)
    rdA(As, 0, av0);                           // 4 ds
    rdA(As, 1, av1);                           // 8 ds
    LGKM(4);                                   // q0 ready; q1 in flight
    mfma16(av0, bvc, acc[0], acc[1]);          // q0
    if (pf2) stA4(slotStage, t + 2);           // 4 vmem (after B loads)
    rdA(As, 2, av0);                           // q1+q2 in flight
    LGKM(4);                                   // q1 ready
    mfma16(av1, bvc, acc[2], acc[3]);          // q1
    rdA(As, 3, av1);                           // q2+q3 in flight
    LGKM(4);                                   // q2 ready
    mfma16(av0, bvc, acc[4], acc[5]);          // q2
    LGKM(0);                                   // q3 ready
    mfma16(av1, bvc, acc[6], acc[7]);          // q3

    // boundary: drain stA(t+1) + B(t+1); keep stA(t+2) in flight
    if (pf2)      { VMCNT(4); }
    else if (nx)  { VMCNT(0); }
    if (nx) BARRIER();
  };

  int a0 = 0, a1 = 1, a2 = 2;   // LDS slots of tiles t, t+1, t+2
  for (int t = 0; t < NT; t += 2) {
    body(t,     &lds[a0 * 16384], a2, bvA, bvB);   // even: cur B in bvA
    body(t + 1, &lds[a1 * 16384], a0, bvB, bvA);   // odd:  cur B in bvB
    int n0 = a2, n1 = a0, n2 = a1;                 // advance by 2 tiles
    a0 = n0; a1 = n1; a2 = n2;
  }

  // epilogue: C/D layout col=lane&15, row=(lane>>4)*4+reg
  const int colg0 = bn * BN + wn * 64 + lane15;
  const int rowg0 = bm * BM + wm * 128 + (lane >> 4) * 4;
#pragma unroll
  for (int ni = 0; ni < 4; ++ni) {
    const int colg = colg0 + ni * 16;
    const float bvs = bias[colg];
#pragma unroll
    for (int mi = 0; mi < 8; ++mi) {
      const int rowg = rowg0 + mi * 16;
#pragma unroll
      for (int r = 0; r < 4; ++r)
        C[(size_t)(rowg + r) * OUT_F + colg] = acc[mi][ni][r] + bvs;
    }
  }
}

// ---------------- fallback (only if ws too small) ----------------

__global__ void fallback_kernel(const float* __restrict__ x,
                                const float* __restrict__ wmu,
                                const float* __restrict__ wrho,
                                const float* __restrict__ weps,
                                const float* __restrict__ bmu,
                                const float* __restrict__ brho,
                                const float* __restrict__ beps,
                                float* __restrict__ out) {
  int o = blockIdx.x * blockDim.x + threadIdx.x;
  int t = blockIdx.y;
  float s = 0.f;
  const float* xr = x + (size_t)t * IN_F;
  const float* wm = wmu + (size_t)o * IN_F;
  const float* wr = wrho + (size_t)o * IN_F;
  const float* we = weps + (size_t)o * IN_F;
  for (int k = 0; k < IN_F; ++k)
    s += xr[k] * fmaf(softplus_f(wr[k]), we[k], wm[k]);
  out[(size_t)t * OUT_F + o] = s + fmaf(softplus_f(brho[o]), beps[o], bmu[o]);
}

// ---------------- launch ----------------

extern "C" void kernel_launch(void* const* d_in, const int* in_sizes, int n_in,
                              void* d_out, int out_size, void* d_ws, size_t ws_size,
                              hipStream_t stream) {
  const float* x    = (const float*)d_in[0];
  const float* wmu  = (const float*)d_in[1];
  const float* wrho = (const float*)d_in[2];
  const float* bmu  = (const float*)d_in[3];
  const float* brho = (const float*)d_in[4];
  const float* weps = (const float*)d_in[5];
  const float* beps = (const float*)d_in[6];
  float* out = (float*)d_out;

  const size_t xb_off   = 0;
  const size_t wb_off   = (size_t)TOKENS * IN_F * 2;            // 64 MB
  const size_t bias_off = wb_off + (size_t)OUT_F * IN_F * 2;    // +32 MB
  const size_t needed   = bias_off + (size_t)OUT_F * 4;

  if (ws_size < needed) {
    dim3 g(OUT_F / 256, TOKENS);
    hipLaunchKernelGGL(fallback_kernel, g, dim3(256), 0, stream,
                       x, wmu, wrho, weps, bmu, brho, beps, out);
    return;
  }

  unsigned short* xb = (unsigned short*)((char*)d_ws + xb_off);
  unsigned short* wb = (unsigned short*)((char*)d_ws + wb_off);
  float* bias = (float*)((char*)d_ws + bias_off);

  hipLaunchKernelGGL(prep_kernel, dim3(2048), dim3(256), 0, stream,
                     x, wmu, wrho, weps, bmu, brho, beps, xb, wb, bias);

  hipLaunchKernelGGL(gemm_bt_kernel,
                     dim3((TOKENS / BM) * (OUT_F / BN)), dim3(THREADS), 0, stream,
                     xb, wb, bias, out);
}

// Round 15
// 326.049 us; speedup vs baseline: 1.3230x; 1.3230x over previous
//
#include <hip/hip_runtime.h>
#include <hip/hip_bf16.h>
#include <cstdint>

#define TOKENS 8192
#define IN_F   4096
#define OUT_F  4096

#define BM 256
#define BN 256
#define BK 64
#define NT (IN_F / BK)   // 64 K-tiles
#define THREADS 512

typedef __attribute__((ext_vector_type(8))) short bf16x8;
typedef __attribute__((ext_vector_type(4))) float f32x4;

#define GLOBAL_AS __attribute__((address_space(1)))
#define LDS_AS    __attribute__((address_space(3)))

#define BARRIER() __builtin_amdgcn_s_barrier()
#define LGKM(n)   do { asm volatile("s_waitcnt lgkmcnt(" #n ")"); \
                       __builtin_amdgcn_sched_barrier(0); } while (0)
#define VMCNT(n)  do { asm volatile("s_waitcnt vmcnt(" #n ")"); \
                       __builtin_amdgcn_sched_barrier(0); } while (0)

__device__ __forceinline__ unsigned short f2bf(float f) {
  union { float f; unsigned int u; } v;
  v.f = f;
  unsigned int r = 0x7FFFu + ((v.u >> 16) & 1u);
  return (unsigned short)((v.u + r) >> 16);
}

__device__ __forceinline__ float softplus_f(float x) {
  return log1pf(expf(x));
}

// ---------------- fused prep kernel ----------------

#define NW4 ((long long)OUT_F * IN_F / 4)
#define NX4 ((long long)TOKENS * IN_F / 4)
#define NB4 (OUT_F / 4)

__global__ void prep_kernel(const float* __restrict__ x,
                            const float* __restrict__ wmu,
                            const float* __restrict__ wrho,
                            const float* __restrict__ weps,
                            const float* __restrict__ bmu,
                            const float* __restrict__ brho,
                            const float* __restrict__ beps,
                            unsigned short* __restrict__ xb,
                            unsigned short* __restrict__ wb,
                            float* __restrict__ bias) {
  long long i = (long long)blockIdx.x * blockDim.x + threadIdx.x;
  long long stride = (long long)gridDim.x * blockDim.x;
  const long long total = NW4 + NX4 + NB4;
  for (; i < total; i += stride) {
    if (i < NW4) {
      float4 m = reinterpret_cast<const float4*>(wmu)[i];
      float4 r = reinterpret_cast<const float4*>(wrho)[i];
      float4 e = reinterpret_cast<const float4*>(weps)[i];
      ushort4 o;
      o.x = f2bf(fmaf(softplus_f(r.x), e.x, m.x));
      o.y = f2bf(fmaf(softplus_f(r.y), e.y, m.y));
      o.z = f2bf(fmaf(softplus_f(r.z), e.z, m.z));
      o.w = f2bf(fmaf(softplus_f(r.w), e.w, m.w));
      reinterpret_cast<ushort4*>(wb)[i] = o;
    } else if (i < NW4 + NX4) {
      long long j = i - NW4;
      float4 m = reinterpret_cast<const float4*>(x)[j];
      ushort4 o;
      o.x = f2bf(m.x); o.y = f2bf(m.y); o.z = f2bf(m.z); o.w = f2bf(m.w);
      reinterpret_cast<ushort4*>(xb)[j] = o;
    } else {
      long long j = i - NW4 - NX4;
      float4 m = reinterpret_cast<const float4*>(bmu)[j];
      float4 r = reinterpret_cast<const float4*>(brho)[j];
      float4 e = reinterpret_cast<const float4*>(beps)[j];
      float4 o;
      o.x = fmaf(softplus_f(r.x), e.x, m.x);
      o.y = fmaf(softplus_f(r.y), e.y, m.y);
      o.z = fmaf(softplus_f(r.z), e.z, m.z);
      o.w = fmaf(softplus_f(r.w), e.w, m.w);
      reinterpret_cast<float4*>(bias)[j] = o;
    }
  }
}

// ---------------- GEMM: r9 free-flow (best measured) + coalesced epilogue ----------------
// K-loop is byte-identical to r9 (GEMM 235us): A ring 3x32KiB + B ring 2x32KiB,
// 8 waves (2M x 4N), per-wave out 128x64, counted-LGKM quadrant pipeline,
// 2 barriers/tile, VMCNT(6) boundary publish. Proofs unchanged (see r9).
// r15 change: EPILOGUE ONLY. Old: 128 scalar stores/thread at 64B effective
// segments. New: per-wave LDS bounce (wave-private 8.5KB region in the dead
// A-ring, stride 68 f32 to stagger banks) -> global_store_dwordx4 rows with
// 256B-contiguous per 4-lane group. Wave-private => LGKM(0) only, no barriers.
// LDS swizzle: chunk ^= (row & 7) via pre-swizzled global source (linear
// global_load_lds dest) + matching XOR on ds_read (rule 21 involution).

__global__ __launch_bounds__(THREADS, 2) void gemm_bt_kernel(
    const unsigned short* __restrict__ A,   // [TOKENS][IN_F] bf16
    const unsigned short* __restrict__ B,   // [OUT_F][IN_F] bf16
    const float* __restrict__ bias,         // [OUT_F]
    float* __restrict__ C)                  // [TOKENS][OUT_F]
{
  __shared__ unsigned short lds[5 * 16384]; // 160 KiB

  const int tid  = threadIdx.x;
  const int lane = tid & 63;
  const int wave = tid >> 6;   // 0..7
  const int wm   = wave >> 2;  // 0..1
  const int wn   = wave & 3;   // 0..3

  // XCD-aware bijective block swizzle (512 = 8 XCD chunks x 64)
  const int bid = blockIdx.x;
  const int wg  = (bid & 7) * 64 + (bid >> 3);
  const int ch  = wg >> 6;
  const int idx = wg & 63;
  const int bm  = (ch >> 1) * 8 + (idx >> 3);  // 0..31
  const int bn  = (ch & 1) * 8 + (idx & 7);    // 0..15

  const int lane15 = lane & 15;
  const int cgrp   = lane >> 4;                // 0..3
  const int rdoff0 = lane15 * 64 + ((cgrp ^ (lane & 7)) * 8);
  const int rdoff1 = lane15 * 64 + (((4 + cgrp) ^ (lane & 7)) * 8);

  // staging: per-lane pre-swizzled global source
  const int srow = lane >> 3;                  // 0..7
  const int scol = ((lane & 7) ^ srow) * 8;    // swizzled 16B chunk -> elems
  const unsigned short* Asrc = A + (size_t)(bm * BM + wave * 16 + srow) * IN_F + scol;
  const unsigned short* Bsrc = B + (size_t)(bn * BN + wave * 16 + srow) * IN_F + scol;

  f32x4 acc[8][4] = {};

  auto stA = [&](int slot, int half, int t) {
    unsigned short* dst = &lds[slot * 16384 + half * 8192 + wave * 1024];
    const unsigned short* g = Asrc + (size_t)(half * 128) * IN_F + t * BK;
    __builtin_amdgcn_global_load_lds((const GLOBAL_AS void*)g,
                                     (LDS_AS void*)dst, 16, 0, 0);
    __builtin_amdgcn_global_load_lds((const GLOBAL_AS void*)(g + (size_t)8 * IN_F),
                                     (LDS_AS void*)(dst + 512), 16, 0, 0);
  };
  auto stB = [&](int slot, int half, int t) {
    unsigned short* dst = &lds[49152 + slot * 16384 + half * 8192 + wave * 1024];
    const unsigned short* g = Bsrc + (size_t)(half * 128) * IN_F + t * BK;
    __builtin_amdgcn_global_load_lds((const GLOBAL_AS void*)g,
                                     (LDS_AS void*)dst, 16, 0, 0);
    __builtin_amdgcn_global_load_lds((const GLOBAL_AS void*)(g + (size_t)8 * IN_F),
                                     (LDS_AS void*)(dst + 512), 16, 0, 0);
  };

  auto rdA = [&](const unsigned short* Ar, int q, bf16x8 (&av)[2][2]) {
#pragma unroll
    for (int f = 0; f < 2; ++f) {
      const unsigned short* p = Ar + (wm * 128 + q * 32 + f * 16) * 64;
      av[f][0] = *reinterpret_cast<const bf16x8*>(p + rdoff0);
      av[f][1] = *reinterpret_cast<const bf16x8*>(p + rdoff1);
    }
  };
  auto rdB = [&](const unsigned short* Br, bf16x8 (&bv)[4][2]) {
#pragma unroll
    for (int n = 0; n < 4; ++n) {
      const unsigned short* p = Br + (wn * 64 + n * 16) * 64;
      bv[n][0] = *reinterpret_cast<const bf16x8*>(p + rdoff0);
      bv[n][1] = *reinterpret_cast<const bf16x8*>(p + rdoff1);
    }
  };
  auto mfma16 = [&](bf16x8 (&av)[2][2], bf16x8 (&bv)[4][2], f32x4* r0, f32x4* r1) {
    __builtin_amdgcn_s_setprio(1);
#pragma unroll
    for (int kk = 0; kk < 2; ++kk) {
#pragma unroll
      for (int n = 0; n < 4; ++n) {
        r0[n] = __builtin_amdgcn_mfma_f32_16x16x32_bf16(av[0][kk], bv[n][kk], r0[n], 0, 0, 0);
        r1[n] = __builtin_amdgcn_mfma_f32_16x16x32_bf16(av[1][kk], bv[n][kk], r1[n], 0, 0, 0);
      }
    }
    __builtin_amdgcn_s_setprio(0);
  };

  // prologue: stage t0 fully, then t1 fully; wait t0 (8 newest stay in flight)
  stA(0, 0, 0); stA(0, 1, 0); stB(0, 0, 0); stB(0, 1, 0);
  stA(1, 0, 1); stA(1, 1, 1); stB(1, 0, 1); stB(1, 1, 1);
  VMCNT(8);
  BARRIER();

  int aslot = 0, bslot = 0;
  for (int t = 0; t < NT; ++t) {
    const unsigned short* As = &lds[aslot * 16384];
    const unsigned short* Bs = &lds[49152 + bslot * 16384];
    int a2 = aslot + 2; if (a2 >= 3) a2 -= 3;   // A slot of tile t+2
    const bool pf = (t + 2 < NT);
    bf16x8 avX[2][2], avY[2][2], bv[4][2];

    // ---- free-flow body: reads run one quadrant ahead of MFMA ----
    rdB(Bs, bv);                                 // 8 ds
    rdA(As, 0, avX);                             // +4 = 12
    if (pf) { stA(a2, 0, t + 2); stA(a2, 1, t + 2); }   // vm +4
    rdA(As, 1, avY);                             // +4 = 16 outstanding
    LGKM(4);                                     // B + q0 ready; q1 in flight
    mfma16(avX, bv, acc[0], acc[1]);             // q0
    BARRIER();   // bar1: all waves' B reads drained (their LGKM(4)) before stB

    if (pf) stB(bslot, 0, t + 2);                // vm +2
    rdA(As, 2, avX);                             // q1 + q2 in flight
    LGKM(4);                                     // q1 ready
    mfma16(avY, bv, acc[2], acc[3]);             // q1
    if (pf) stB(bslot, 1, t + 2);                // vm +2
    rdA(As, 3, avY);                             // q2 + q3 in flight
    LGKM(4);                                     // q2 ready
    mfma16(avX, bv, acc[4], acc[5]);             // q2
    LGKM(0);                                     // q3 ready
    mfma16(avY, bv, acc[6], acc[7]);             // q3

    // boundary: publish tile t+1 (counted; never drain in steady state)
    if (pf)              { VMCNT(6); }
    else if (t + 1 < NT) { VMCNT(0); }
    if (t + 1 < NT) BARRIER();                   // bar2

    aslot = (aslot == 2) ? 0 : aslot + 1;
    bslot ^= 1;
  }

  // ---- epilogue (r15): per-wave LDS bounce -> coalesced dwordx4 stores ----
  // Wave-private region: 16 rows x stride 68 f32 = 4352B (< 10KB/wave in the
  // 160KB, now-dead LDS). All K-loop LDS reads are drained (LGKM(0) below
  // precedes first ds_write; barrier not needed — region is wave-private
  // within the 5*16384-short buffer partitioned by wave).
  float* eplds = reinterpret_cast<float*>(&lds[wave * 10240]);  // 20KB shorts = 10KB... per-wave 10240 shorts = 20KB? No: shorts*2B; 10240 shorts = 20KB. 8 waves x 20KB = 160KB total, need 4.25KB each: fits.
  const int colg0 = bn * BN + wn * 64 + lane15;
  const int rowg0 = bm * BM + wm * 128 + (lane >> 4) * 4;
  float bvv[4];
#pragma unroll
  for (int ni = 0; ni < 4; ++ni) bvv[ni] = bias[colg0 + ni * 16];

  LGKM(0);   // ensure all K-loop ds traffic of this wave is retired
#pragma unroll
  for (int mi = 0; mi < 8; ++mi) {
    // write 16x64 chunk (rows rowg0-base + mi*16 .. +15), bank-staggered
#pragma unroll
    for (int ni = 0; ni < 4; ++ni)
#pragma unroll
      for (int r = 0; r < 4; ++r)
        eplds[((lane >> 4) * 4 + r) * 68 + ni * 16 + lane15] = acc[mi][ni][r] + bvv[ni];
    LGKM(0);
    // read back one quarter-row (16 f32 = 4 x f32x4) per lane and store
    const int rr = lane >> 2;          // 0..15
    const int cc = (lane & 3) * 16;    // 0,16,32,48
    f32x4 v0 = *reinterpret_cast<const f32x4*>(&eplds[rr * 68 + cc + 0]);
    f32x4 v1 = *reinterpret_cast<const f32x4*>(&eplds[rr * 68 + cc + 4]);
    f32x4 v2 = *reinterpret_cast<const f32x4*>(&eplds[rr * 68 + cc + 8]);
    f32x4 v3 = *reinterpret_cast<const f32x4*>(&eplds[rr * 68 + cc + 12]);
    const int rowg = bm * BM + wm * 128 + mi * 16 + rr;
    const int colg = bn * BN + wn * 64 + cc;
    float* cp = &C[(size_t)rowg * OUT_F + colg];
    *reinterpret_cast<f32x4*>(cp + 0)  = v0;
    *reinterpret_cast<f32x4*>(cp + 4)  = v1;
    *reinterpret_cast<f32x4*>(cp + 8)  = v2;
    *reinterpret_cast<f32x4*>(cp + 12) = v3;
    LGKM(0);   // region reuse safe for next mi (wave-private, in-order DS)
  }
}

// ---------------- fallback (only if ws too small) ----------------

__global__ void fallback_kernel(const float* __restrict__ x,
                                const float* __restrict__ wmu,
                                const float* __restrict__ wrho,
                                const float* __restrict__ weps,
                                const float* __restrict__ bmu,
                                const float* __restrict__ brho,
                                const float* __restrict__ beps,
                                float* __restrict__ out) {
  int o = blockIdx.x * blockDim.x + threadIdx.x;
  int t = blockIdx.y;
  float s = 0.f;
  const float* xr = x + (size_t)t * IN_F;
  const float* wm = wmu + (size_t)o * IN_F;
  const float* wr = wrho + (size_t)o * IN_F;
  const float* we = weps + (size_t)o * IN_F;
  for (int k = 0; k < IN_F; ++k)
    s += xr[k] * fmaf(softplus_f(wr[k]), we[k], wm[k]);
  out[(size_t)t * OUT_F + o] = s + fmaf(softplus_f(brho[o]), beps[o], bmu[o]);
}

// ---------------- launch ----------------

extern "C" void kernel_launch(void* const* d_in, const int* in_sizes, int n_in,
                              void* d_out, int out_size, void* d_ws, size_t ws_size,
                              hipStream_t stream) {
  const float* x    = (const float*)d_in[0];
  const float* wmu  = (const float*)d_in[1];
  const float* wrho = (const float*)d_in[2];
  const float* bmu  = (const float*)d_in[3];
  const float* brho = (const float*)d_in[4];
  const float* weps = (const float*)d_in[5];
  const float* beps = (const float*)d_in[6];
  float* out = (float*)d_out;

  const size_t xb_off   = 0;
  const size_t wb_off   = (size_t)TOKENS * IN_F * 2;            // 64 MB
  const size_t bias_off = wb_off + (size_t)OUT_F * IN_F * 2;    // +32 MB
  const size_t needed   = bias_off + (size_t)OUT_F * 4;

  if (ws_size < needed) {
    dim3 g(OUT_F / 256, TOKENS);
    hipLaunchKernelGGL(fallback_kernel, g, dim3(256), 0, stream,
                       x, wmu, wrho, weps, bmu, brho, beps, out);
    return;
  }

  unsigned short* xb = (unsigned short*)((char*)d_ws + xb_off);
  unsigned short* wb = (unsigned short*)((char*)d_ws + wb_off);
  float* bias = (float*)((char*)d_ws + bias_off);

  hipLaunchKernelGGL(prep_kernel, dim3(2048), dim3(256), 0, stream,
                     x, wmu, wrho, weps, bmu, brho, beps, xb, wb, bias);

  hipLaunchKernelGGL(gemm_bt_kernel,
                     dim3((TOKENS / BM) * (OUT_F / BN)), dim3(THREADS), 0, stream,
                     xb, wb, bias, out);
}